// Round 1
// baseline (1288.041 us; speedup 1.0000x reference)
//
#include <hip/hip_runtime.h>
#include <math.h>

#define SB   2
#define SEQ  2048
#define FDIM 1024
#define NH   16
#define HD   64

// ---------------------------------------------------------------------------
// GEMM: C = A @ W + bias.  A:[M,K] f32 row-major, W:[K,N] row-major, bias[N].
// 64x64 output tile, BK=32, 256 threads (16x16, each 4x4).
// OUTMODE 0: plain C1[m*N+n]
// OUTMODE 1: Q head layout  C1[((b*NH+h)*SEQ+s)*HD+dd]
// OUTMODE 2: split KV: n<FDIM -> C1 (K), else C2 (V), head layout
// ---------------------------------------------------------------------------
template <int OUTMODE>
__global__ __launch_bounds__(256) void gemm_bias(
    const float* __restrict__ A, const float* __restrict__ W,
    const float* __restrict__ bias, float* __restrict__ C1,
    float* __restrict__ C2, int M, int N, int K)
{
    __shared__ float4 As4[32][17];   // A transposed: As[k][m], stride 68 floats
    __shared__ float4 Bs4[32][17];   // B row-major:  Bs[k][n]
    float* Asf = (float*)As4;

    const int tid = threadIdx.x;
    const int tx = tid & 15, ty = tid >> 4;
    const int m0 = blockIdx.y * 64, n0 = blockIdx.x * 64;

    float acc[4][4] = {};

    for (int k0 = 0; k0 < K; k0 += 32) {
        // A tile 64x32 -> transposed LDS
        #pragma unroll
        for (int i = 0; i < 2; i++) {
            int idx = tid + i * 256;
            int row = idx >> 3, c4 = idx & 7;
            float4 a = *(const float4*)(A + (size_t)(m0 + row) * K + k0 + c4 * 4);
            int kb = c4 * 4;
            Asf[(kb + 0) * 68 + row] = a.x;
            Asf[(kb + 1) * 68 + row] = a.y;
            Asf[(kb + 2) * 68 + row] = a.z;
            Asf[(kb + 3) * 68 + row] = a.w;
        }
        // W tile 32x64 -> row-major LDS (coalesced 256B rows)
        #pragma unroll
        for (int i = 0; i < 2; i++) {
            int idx = tid + i * 256;
            int row = idx >> 4, c4 = idx & 15;
            Bs4[row][c4] = *(const float4*)(W + (size_t)(k0 + row) * N + n0 + c4 * 4);
        }
        __syncthreads();
        #pragma unroll
        for (int kk = 0; kk < 32; kk++) {
            float4 a4 = As4[kk][ty];   // 4 m-rows, broadcast across tx
            float4 b4 = Bs4[kk][tx];   // 4 n-cols, spread across banks
            float av[4] = {a4.x, a4.y, a4.z, a4.w};
            float bv[4] = {b4.x, b4.y, b4.z, b4.w};
            #pragma unroll
            for (int i = 0; i < 4; i++)
                #pragma unroll
                for (int j = 0; j < 4; j++)
                    acc[i][j] += av[i] * bv[j];
        }
        __syncthreads();
    }

    float4 bi = *(const float4*)(bias + n0 + tx * 4);
    #pragma unroll
    for (int i = 0; i < 4; i++) {
        int m = m0 + ty * 4 + i;
        float4 v;
        v.x = acc[i][0] + bi.x; v.y = acc[i][1] + bi.y;
        v.z = acc[i][2] + bi.z; v.w = acc[i][3] + bi.w;
        if (OUTMODE == 0) {
            *(float4*)(C1 + (size_t)m * N + n0 + tx * 4) = v;
        } else if (OUTMODE == 1) {
            int bb = m >> 11, s = m & (SEQ - 1);
            int h = n0 >> 6;   // one head per 64-wide n tile
            *(float4*)(C1 + ((size_t)(bb * NH + h) * SEQ + s) * HD + tx * 4) = v;
        } else {
            int bb = m >> 11, z = m & (SEQ - 1);
            float* Cd = (n0 < FDIM) ? C1 : C2;
            int h = ((n0 < FDIM) ? n0 : (n0 - FDIM)) >> 6;
            *(float4*)(Cd + ((size_t)(bb * NH + h) * SEQ + z) * HD + tx * 4) = v;
        }
    }
}

// ---------------------------------------------------------------------------
// Flash-style masked attention, fp32. One block = (b, h, 64-row s-tile).
// Masked logits set to exactly -1e12f (matches ref fp32 rounding: row 0 is
// fully masked -> uniform softmax over all Z; rows s>=1 attend z<s).
// LDS: Qt[d][r], KPt (K transposed [d][z], reused for P transposed [z][r]),
// V row-major [z][d]. Row max/sum via 16-lane shfl_xor (row-group = 16 lanes).
// ---------------------------------------------------------------------------
__global__ __launch_bounds__(256) void attn_kernel(
    const float* __restrict__ Qg, const float* __restrict__ Kg,
    const float* __restrict__ Vg, float* __restrict__ Og)
{
    __shared__ float4 Qt4[64][17];    // Qt[dd][r]
    __shared__ float4 KPt4[64][17];   // Kt[dd][z]  then  Pt[z][r]
    __shared__ float4 Vr4[64][17];    // V[z][dd]
    float* Qtf  = (float*)Qt4;
    float* KPtf = (float*)KPt4;

    const int tid = threadIdx.x;
    const int tx = tid & 15, ty = tid >> 4;
    const int bid = blockIdx.x;
    const int st = bid & 31;          // s-tile index (SEQ/64 = 32)
    const int h  = (bid >> 5) & (NH - 1);
    const int b  = bid >> 9;
    const int s0 = st << 6;

    const float* Qb = Qg + (size_t)(b * NH + h) * SEQ * HD;
    const float* Kb = Kg + (size_t)(b * NH + h) * SEQ * HD;
    const float* Vb = Vg + (size_t)(b * NH + h) * SEQ * HD;

    // Q tile -> transposed LDS
    #pragma unroll
    for (int i = 0; i < 4; i++) {
        int idx = tid + i * 256;
        int row = idx >> 4, c4 = idx & 15;
        float4 q = *(const float4*)(Qb + (size_t)(s0 + row) * HD + c4 * 4);
        int dd = c4 * 4;
        Qtf[(dd + 0) * 68 + row] = q.x;
        Qtf[(dd + 1) * 68 + row] = q.y;
        Qtf[(dd + 2) * 68 + row] = q.z;
        Qtf[(dd + 3) * 68 + row] = q.w;
    }

    float m_run[4], l_run[4], oacc[4][4];
    #pragma unroll
    for (int i = 0; i < 4; i++) {
        m_run[i] = -INFINITY; l_run[i] = 0.f;
        #pragma unroll
        for (int j = 0; j < 4; j++) oacc[i][j] = 0.f;
    }

    // row 0 attends (uniformly) to ALL z -> its s-tile sweeps every z-tile.
    const int ntiles = (st == 0) ? (SEQ / 64) : (st + 1);

    for (int zt = 0; zt < ntiles; zt++) {
        const int z0 = zt << 6;
        __syncthreads();   // prior-iter Pt/V reads done (and Q load, iter 0)

        // K tile -> transposed LDS; V tile -> row-major LDS
        #pragma unroll
        for (int i = 0; i < 4; i++) {
            int idx = tid + i * 256;
            int row = idx >> 4, c4 = idx & 15;
            float4 k = *(const float4*)(Kb + (size_t)(z0 + row) * HD + c4 * 4);
            int dd = c4 * 4;
            KPtf[(dd + 0) * 68 + row] = k.x;
            KPtf[(dd + 1) * 68 + row] = k.y;
            KPtf[(dd + 2) * 68 + row] = k.z;
            KPtf[(dd + 3) * 68 + row] = k.w;
            Vr4[row][c4] = *(const float4*)(Vb + (size_t)(z0 + row) * HD + c4 * 4);
        }
        __syncthreads();

        // S = Q K^T (64x64), thread owns rows 4ty..+3, cols 4tx..+3
        float sacc[4][4] = {};
        #pragma unroll
        for (int dd = 0; dd < 64; dd++) {
            float4 qa = Qt4[dd][ty];
            float4 kb = KPt4[dd][tx];
            float qv[4] = {qa.x, qa.y, qa.z, qa.w};
            float kv[4] = {kb.x, kb.y, kb.z, kb.w};
            #pragma unroll
            for (int i = 0; i < 4; i++)
                #pragma unroll
                for (int j = 0; j < 4; j++)
                    sacc[i][j] += qv[i] * kv[j];
        }
        // mask: z >= s  ->  exactly -1e12 (diagonal included)
        #pragma unroll
        for (int i = 0; i < 4; i++) {
            int srow = s0 + ty * 4 + i;
            #pragma unroll
            for (int j = 0; j < 4; j++) {
                int zc = z0 + tx * 4 + j;
                if (zc >= srow) sacc[i][j] = -1e12f;
            }
        }

        // online softmax; row-group = 16 lanes sharing ty -> shfl_xor reduce
        float m_new[4], p[4][4], alpha[4];
        #pragma unroll
        for (int i = 0; i < 4; i++) {
            float rm = fmaxf(fmaxf(sacc[i][0], sacc[i][1]),
                             fmaxf(sacc[i][2], sacc[i][3]));
            #pragma unroll
            for (int off = 8; off >= 1; off >>= 1)
                rm = fmaxf(rm, __shfl_xor(rm, off, 64));
            m_new[i] = fmaxf(m_run[i], rm);
            float rs = 0.f;
            #pragma unroll
            for (int j = 0; j < 4; j++) {
                p[i][j] = __expf(sacc[i][j] - m_new[i]);
                rs += p[i][j];
            }
            #pragma unroll
            for (int off = 8; off >= 1; off >>= 1)
                rs += __shfl_xor(rs, off, 64);
            alpha[i] = __expf(m_run[i] - m_new[i]);   // m_run=-inf -> 0
            l_run[i] = alpha[i] * l_run[i] + rs;
            m_run[i] = m_new[i];
            #pragma unroll
            for (int j = 0; j < 4; j++) oacc[i][j] *= alpha[i];
        }

        __syncthreads();   // all waves done reading Kt before P overwrites it
        #pragma unroll
        for (int i = 0; i < 4; i++) {
            int r = ty * 4 + i;
            #pragma unroll
            for (int j = 0; j < 4; j++)
                KPtf[(size_t)(tx * 4 + j) * 68 + r] = p[i][j];  // Pt[z][r]
        }
        __syncthreads();

        // O += P @ V : oacc[i][j] += sum_z Pt[z][r_i] * V[z][c_j]
        #pragma unroll
        for (int z = 0; z < 64; z++) {
            float4 pa = KPt4[z][ty];
            float4 vb = Vr4[z][tx];
            float pv[4] = {pa.x, pa.y, pa.z, pa.w};
            float vv[4] = {vb.x, vb.y, vb.z, vb.w};
            #pragma unroll
            for (int i = 0; i < 4; i++)
                #pragma unroll
                for (int j = 0; j < 4; j++)
                    oacc[i][j] += pv[i] * vv[j];
        }
    }

    // epilogue: divide by softmax denom, store O in [B,S,F] layout
    #pragma unroll
    for (int i = 0; i < 4; i++) {
        int srow = s0 + ty * 4 + i;
        float inv = 1.0f / l_run[i];
        float4 o;
        o.x = oacc[i][0] * inv; o.y = oacc[i][1] * inv;
        o.z = oacc[i][2] * inv; o.w = oacc[i][3] * inv;
        *(float4*)(Og + (size_t)(b * SEQ + srow) * FDIM + h * HD + tx * 4) = o;
    }
}

// ---------------------------------------------------------------------------
extern "C" void kernel_launch(void* const* d_in, const int* in_sizes, int n_in,
                              void* d_out, int out_size, void* d_ws, size_t ws_size,
                              hipStream_t stream) {
    const float* attend_from = (const float*)d_in[0];
    const float* attend_to   = (const float*)d_in[1];
    const float* w_q   = (const float*)d_in[2];
    const float* b_q   = (const float*)d_in[3];
    const float* w_kv  = (const float*)d_in[4];
    const float* b_kv  = (const float*)d_in[5];
    const float* w_out = (const float*)d_in[6];
    const float* b_out = (const float*)d_in[7];
    float* out = (float*)d_out;

    float* ws = (float*)d_ws;
    const size_t QN = (size_t)SB * NH * SEQ * HD;   // 4M floats each
    float* Q = ws;
    float* K = ws + QN;
    float* V = ws + 2 * QN;
    float* O = ws + 3 * QN;

    dim3 blk(256);
    const int M = SB * SEQ;   // 4096

    gemm_bias<1><<<dim3(FDIM / 64, M / 64), blk, 0, stream>>>(
        attend_from, w_q, b_q, Q, nullptr, M, FDIM, FDIM);
    gemm_bias<2><<<dim3(2 * FDIM / 64, M / 64), blk, 0, stream>>>(
        attend_to, w_kv, b_kv, K, V, M, 2 * FDIM, FDIM);
    attn_kernel<<<dim3(SB * NH * (SEQ / 64)), blk, 0, stream>>>(Q, K, V, O);
    gemm_bias<0><<<dim3(FDIM / 64, M / 64), blk, 0, stream>>>(
        O, w_out, b_out, out, nullptr, M, FDIM, FDIM);
}

// Round 2
// 630.352 us; speedup vs baseline: 2.0434x; 2.0434x over previous
//
#include <hip/hip_runtime.h>
#include <math.h>

#define SB   2
#define SEQ  2048
#define FDIM 1024
#define NH   16
#define HD   64
#define BH   (SB * NH)   // 32
#define LK   72          // LDS row stride in bf16 elems (64 + 8 pad)

typedef __attribute__((ext_vector_type(8))) short short8;
typedef __attribute__((ext_vector_type(4))) float floatx4;

__device__ __forceinline__ unsigned pk_bf16(float a, float b) {
    unsigned ua = __builtin_bit_cast(unsigned, a);
    unsigned ub = __builtin_bit_cast(unsigned, b);
    ua += 0x7fffu + ((ua >> 16) & 1u);       // RNE
    ub += 0x7fffu + ((ub >> 16) & 1u);
    return (ua >> 16) | (ub & 0xffff0000u);
}
__device__ __forceinline__ unsigned short bf16_1(float a) {
    unsigned ua = __builtin_bit_cast(unsigned, a);
    ua += 0x7fffu + ((ua >> 16) & 1u);
    return (unsigned short)(ua >> 16);
}

// ---------------------------------------------------------------------------
// fp32 GEMM: C = A @ W + bias (unchanged from round 1 — known good).
// ---------------------------------------------------------------------------
template <int OUTMODE>
__global__ __launch_bounds__(256) void gemm_bias(
    const float* __restrict__ A, const float* __restrict__ W,
    const float* __restrict__ bias, float* __restrict__ C1,
    float* __restrict__ C2, int M, int N, int K)
{
    __shared__ float4 As4[32][17];
    __shared__ float4 Bs4[32][17];
    float* Asf = (float*)As4;

    const int tid = threadIdx.x;
    const int tx = tid & 15, ty = tid >> 4;
    const int m0 = blockIdx.y * 64, n0 = blockIdx.x * 64;

    float acc[4][4] = {};

    for (int k0 = 0; k0 < K; k0 += 32) {
        #pragma unroll
        for (int i = 0; i < 2; i++) {
            int idx = tid + i * 256;
            int row = idx >> 3, c4 = idx & 7;
            float4 a = *(const float4*)(A + (size_t)(m0 + row) * K + k0 + c4 * 4);
            int kb = c4 * 4;
            Asf[(kb + 0) * 68 + row] = a.x;
            Asf[(kb + 1) * 68 + row] = a.y;
            Asf[(kb + 2) * 68 + row] = a.z;
            Asf[(kb + 3) * 68 + row] = a.w;
        }
        #pragma unroll
        for (int i = 0; i < 2; i++) {
            int idx = tid + i * 256;
            int row = idx >> 4, c4 = idx & 15;
            Bs4[row][c4] = *(const float4*)(W + (size_t)(k0 + row) * N + n0 + c4 * 4);
        }
        __syncthreads();
        #pragma unroll
        for (int kk = 0; kk < 32; kk++) {
            float4 a4 = As4[kk][ty];
            float4 b4 = Bs4[kk][tx];
            float av[4] = {a4.x, a4.y, a4.z, a4.w};
            float bv[4] = {b4.x, b4.y, b4.z, b4.w};
            #pragma unroll
            for (int i = 0; i < 4; i++)
                #pragma unroll
                for (int j = 0; j < 4; j++)
                    acc[i][j] += av[i] * bv[j];
        }
        __syncthreads();
    }

    float4 bi = *(const float4*)(bias + n0 + tx * 4);
    #pragma unroll
    for (int i = 0; i < 4; i++) {
        int m = m0 + ty * 4 + i;
        float4 v;
        v.x = acc[i][0] + bi.x; v.y = acc[i][1] + bi.y;
        v.z = acc[i][2] + bi.z; v.w = acc[i][3] + bi.w;
        if (OUTMODE == 0) {
            *(float4*)(C1 + (size_t)m * N + n0 + tx * 4) = v;
        } else if (OUTMODE == 1) {
            int bb = m >> 11, s = m & (SEQ - 1);
            int h = n0 >> 6;
            *(float4*)(C1 + ((size_t)(bb * NH + h) * SEQ + s) * HD + tx * 4) = v;
        } else {
            int bb = m >> 11, z = m & (SEQ - 1);
            float* Cd = (n0 < FDIM) ? C1 : C2;
            int h = ((n0 < FDIM) ? n0 : (n0 - FDIM)) >> 6;
            *(float4*)(Cd + ((size_t)(bb * NH + h) * SEQ + z) * HD + tx * 4) = v;
        }
    }
}

// ---------------------------------------------------------------------------
// V [bh][z][d] -> Vt [bh][d][z]  (fp32, LDS tiled transpose)
// ---------------------------------------------------------------------------
__global__ __launch_bounds__(256) void transpose_v(
    const float* __restrict__ V, float* __restrict__ Vt)
{
    __shared__ float T[64 * 65];
    const int tid = threadIdx.x;
    const int zt = blockIdx.x & 31, bh = blockIdx.x >> 5;
    const int z0 = zt << 6;
    #pragma unroll
    for (int i = 0; i < 4; ++i) {
        int idx = tid + (i << 8);
        int row = idx >> 4, c4 = idx & 15;
        float4 v = *(const float4*)(V + ((size_t)bh * SEQ + z0 + row) * HD + (c4 << 2));
        float* tp = &T[row * 65 + (c4 << 2)];
        tp[0] = v.x; tp[1] = v.y; tp[2] = v.z; tp[3] = v.w;
    }
    __syncthreads();
    #pragma unroll
    for (int i = 0; i < 4; ++i) {
        int idx = tid + (i << 8);
        int d = idx >> 4, c4 = idx & 15;
        float4 o;
        o.x = T[(c4 * 4 + 0) * 65 + d];
        o.y = T[(c4 * 4 + 1) * 65 + d];
        o.z = T[(c4 * 4 + 2) * 65 + d];
        o.w = T[(c4 * 4 + 3) * 65 + d];
        *(float4*)(Vt + ((size_t)bh * HD + d) * SEQ + z0 + (c4 << 2)) = o;
    }
}

// ---------------------------------------------------------------------------
// Flash attention, bf16 MFMA 16x16x32, fp32 softmax.
// Block = (b,h, 64-row s-tile); 4 waves, wave w owns rows [16w,16w+16).
// MFMA layouts (m89-verified): A[m=lane&15][k=quad*8+j], B[k=quad*8+j][n=lane&15],
// C/D[row=quad*4+reg][col=lane&15].
// Masked logits = exactly -1e12f (row 0 fully masked -> uniform softmax, as ref).
// ---------------------------------------------------------------------------
__global__ __launch_bounds__(256) void attn_kernel(
    const float* __restrict__ Qg, const float* __restrict__ Kg,
    const float* __restrict__ Vtg, float* __restrict__ Og)
{
    __shared__ unsigned short Kl[64 * LK];        // K tile row-major [z][d]
    __shared__ unsigned short Vl[64 * LK];        // Vt tile [d][z]
    __shared__ unsigned short Pl[4 * 16 * LK];    // per-wave P strip [16][64]

    const int tid  = threadIdx.x;
    const int w    = tid >> 6;
    const int lane = tid & 63;
    const int q    = lane >> 4;    // quad
    const int l    = lane & 15;

    const int bid = blockIdx.x;
    const int bh  = bid & (BH - 1);
    const int t_o = bid >> 5;                      // heavy tiles first
    const int st  = (t_o == 0) ? 0 : (32 - t_o);
    const int s0  = st << 6;

    const float* Qb  = Qg  + (size_t)bh * SEQ * HD;
    const float* Kb  = Kg  + (size_t)bh * SEQ * HD;
    const float* Vtb = Vtg + (size_t)bh * HD * SEQ;

    // Q strip for this wave -> A-fragments (held in regs for whole block)
    short8 aQ[2];
    {
        const int srow = s0 + 16 * w + l;
        const float* qp = Qb + (size_t)srow * HD + 8 * q;
        float4 q0 = *(const float4*)(qp);
        float4 q1 = *(const float4*)(qp + 4);
        float4 q2 = *(const float4*)(qp + 32);
        float4 q3 = *(const float4*)(qp + 36);
        union { short8 v; unsigned u[4]; } A0, A1;
        A0.u[0] = pk_bf16(q0.x, q0.y); A0.u[1] = pk_bf16(q0.z, q0.w);
        A0.u[2] = pk_bf16(q1.x, q1.y); A0.u[3] = pk_bf16(q1.z, q1.w);
        A1.u[0] = pk_bf16(q2.x, q2.y); A1.u[1] = pk_bf16(q2.z, q2.w);
        A1.u[2] = pk_bf16(q3.x, q3.y); A1.u[3] = pk_bf16(q3.z, q3.w);
        aQ[0] = A0.v; aQ[1] = A1.v;
    }

    float m_run[4], l_run[4];
    floatx4 oacc[4];
    #pragma unroll
    for (int r = 0; r < 4; ++r) { m_run[r] = -INFINITY; l_run[r] = 0.f; }
    #pragma unroll
    for (int nd = 0; nd < 4; ++nd) oacc[nd] = (floatx4){0.f, 0.f, 0.f, 0.f};

    const int ntiles = (st == 0) ? (SEQ >> 6) : (st + 1);

    for (int zt = 0; zt < ntiles; ++zt) {
        const int z0 = zt << 6;
        __syncthreads();
        // stage K and Vt tiles (fp32 global -> bf16 LDS), coalesced float4
        #pragma unroll
        for (int i = 0; i < 4; ++i) {
            int idx = tid + (i << 8);
            int row = idx >> 4, c4 = idx & 15;
            float4 kk = *(const float4*)(Kb + (size_t)(z0 + row) * HD + (c4 << 2));
            *(uint2*)(&Kl[row * LK + (c4 << 2)]) =
                make_uint2(pk_bf16(kk.x, kk.y), pk_bf16(kk.z, kk.w));
            float4 vv = *(const float4*)(Vtb + (size_t)row * SEQ + z0 + (c4 << 2));
            *(uint2*)(&Vl[row * LK + (c4 << 2)]) =
                make_uint2(pk_bf16(vv.x, vv.y), pk_bf16(vv.z, vv.w));
        }
        __syncthreads();

        // S = Q K^T : wave computes S[16][64] as 4 n-subtiles x 2 k-steps
        floatx4 sacc[4];
        #pragma unroll
        for (int t = 0; t < 4; ++t) {
            sacc[t] = (floatx4){0.f, 0.f, 0.f, 0.f};
            short8 b0 = *(const short8*)(&Kl[(16 * t + l) * LK + 8 * q]);
            short8 b1 = *(const short8*)(&Kl[(16 * t + l) * LK + 8 * q + 32]);
            sacc[t] = __builtin_amdgcn_mfma_f32_16x16x32_bf16(aQ[0], b0, sacc[t], 0, 0, 0);
            sacc[t] = __builtin_amdgcn_mfma_f32_16x16x32_bf16(aQ[1], b1, sacc[t], 0, 0, 0);
        }

        // causal mask (diagonal included): z >= s  ->  exactly -1e12
        #pragma unroll
        for (int t = 0; t < 4; ++t) {
            int z = z0 + 16 * t + l;
            #pragma unroll
            for (int r = 0; r < 4; ++r) {
                int s = s0 + 16 * w + 4 * q + r;
                if (z >= s) sacc[t][r] = -1e12f;
            }
        }

        // online softmax; rows live in 16-lane quad groups
        #pragma unroll
        for (int r = 0; r < 4; ++r) {
            float rm = fmaxf(fmaxf(sacc[0][r], sacc[1][r]),
                             fmaxf(sacc[2][r], sacc[3][r]));
            rm = fmaxf(rm, __shfl_xor(rm, 1, 64));
            rm = fmaxf(rm, __shfl_xor(rm, 2, 64));
            rm = fmaxf(rm, __shfl_xor(rm, 4, 64));
            rm = fmaxf(rm, __shfl_xor(rm, 8, 64));
            float mn = fmaxf(m_run[r], rm);
            float rs = 0.f;
            #pragma unroll
            for (int t = 0; t < 4; ++t) {
                float pe = __expf(sacc[t][r] - mn);
                sacc[t][r] = pe;                 // sacc becomes P
                rs += pe;
            }
            rs += __shfl_xor(rs, 1, 64);
            rs += __shfl_xor(rs, 2, 64);
            rs += __shfl_xor(rs, 4, 64);
            rs += __shfl_xor(rs, 8, 64);
            float alpha = __expf(m_run[r] - mn);  // -inf -> 0 on first tile
            l_run[r] = alpha * l_run[r] + rs;
            m_run[r] = mn;
            #pragma unroll
            for (int nd = 0; nd < 4; ++nd) oacc[nd][r] *= alpha;
        }

        // P (C-layout regs) -> per-wave LDS strip as bf16 (no barrier needed)
        unsigned short* Pw = &Pl[w * 16 * LK];
        #pragma unroll
        for (int t = 0; t < 4; ++t)
            #pragma unroll
            for (int r = 0; r < 4; ++r)
                Pw[(4 * q + r) * LK + 16 * t + l] = bf16_1(sacc[t][r]);

        // O += P @ V
        short8 aP0 = *(const short8*)(&Pw[l * LK + 8 * q]);
        short8 aP1 = *(const short8*)(&Pw[l * LK + 8 * q + 32]);
        #pragma unroll
        for (int nd = 0; nd < 4; ++nd) {
            short8 b0 = *(const short8*)(&Vl[(16 * nd + l) * LK + 8 * q]);
            short8 b1 = *(const short8*)(&Vl[(16 * nd + l) * LK + 8 * q + 32]);
            oacc[nd] = __builtin_amdgcn_mfma_f32_16x16x32_bf16(aP0, b0, oacc[nd], 0, 0, 0);
            oacc[nd] = __builtin_amdgcn_mfma_f32_16x16x32_bf16(aP1, b1, oacc[nd], 0, 0, 0);
        }
    }

    // epilogue: O / l  -> [B,S,F]
    const int b = bh >> 4, h = bh & 15;
    #pragma unroll
    for (int r = 0; r < 4; ++r) {
        float inv = 1.0f / l_run[r];
        int s = s0 + 16 * w + 4 * q + r;
        float* op = Og + ((size_t)b * SEQ + s) * FDIM + h * HD;
        #pragma unroll
        for (int nd = 0; nd < 4; ++nd)
            op[16 * nd + l] = oacc[nd][r] * inv;
    }
}

// ---------------------------------------------------------------------------
extern "C" void kernel_launch(void* const* d_in, const int* in_sizes, int n_in,
                              void* d_out, int out_size, void* d_ws, size_t ws_size,
                              hipStream_t stream) {
    const float* attend_from = (const float*)d_in[0];
    const float* attend_to   = (const float*)d_in[1];
    const float* w_q   = (const float*)d_in[2];
    const float* b_q   = (const float*)d_in[3];
    const float* w_kv  = (const float*)d_in[4];
    const float* b_kv  = (const float*)d_in[5];
    const float* w_out = (const float*)d_in[6];
    const float* b_out = (const float*)d_in[7];
    float* out = (float*)d_out;

    float* ws = (float*)d_ws;
    const size_t QN = (size_t)BH * SEQ * HD;   // 4M floats
    float* Q  = ws;
    float* K  = ws + QN;
    float* V  = ws + 2 * QN;   // row-major V, later reused as O
    float* Vt = ws + 3 * QN;
    float* O  = V;             // attn overwrites V (only Vt is read there)

    dim3 blk(256);
    const int M = SB * SEQ;    // 4096

    gemm_bias<1><<<dim3(FDIM / 64, M / 64), blk, 0, stream>>>(
        attend_from, w_q, b_q, Q, nullptr, M, FDIM, FDIM);
    gemm_bias<2><<<dim3(2 * FDIM / 64, M / 64), blk, 0, stream>>>(
        attend_to, w_kv, b_kv, K, V, M, 2 * FDIM, FDIM);
    transpose_v<<<dim3(BH * (SEQ / 64)), blk, 0, stream>>>(V, Vt);
    attn_kernel<<<dim3(BH * (SEQ / 64)), blk, 0, stream>>>(Q, K, Vt, O);
    gemm_bias<0><<<dim3(FDIM / 64, M / 64), blk, 0, stream>>>(
        O, w_out, b_out, out, nullptr, M, FDIM, FDIM);
}

// Round 3
// 264.407 us; speedup vs baseline: 4.8714x; 2.3840x over previous
//
#include <hip/hip_runtime.h>
#include <math.h>

#define SB   2
#define SEQ  2048
#define FDIM 1024
#define NH   16
#define HD   64
#define BH   (SB * NH)   // 32
#define LK   72          // attention LDS row stride in bf16 elems (64 + 8 pad)

typedef __attribute__((ext_vector_type(8))) short short8;
typedef __attribute__((ext_vector_type(4))) float floatx4;

__device__ __forceinline__ unsigned pk_bf16(float a, float b) {
    unsigned ua = __builtin_bit_cast(unsigned, a);
    unsigned ub = __builtin_bit_cast(unsigned, b);
    ua += 0x7fffu + ((ua >> 16) & 1u);       // RNE
    ub += 0x7fffu + ((ub >> 16) & 1u);
    return (ua >> 16) | (ub & 0xffff0000u);
}
__device__ __forceinline__ unsigned short bf16_1(float a) {
    unsigned ua = __builtin_bit_cast(unsigned, a);
    ua += 0x7fffu + ((ua >> 16) & 1u);
    return (unsigned short)(ua >> 16);
}
__device__ __forceinline__ void load16_lds(const unsigned short* g, unsigned short* l) {
    __builtin_amdgcn_global_load_lds(
        (const __attribute__((address_space(1))) unsigned int*)g,
        (__attribute__((address_space(3))) unsigned int*)l, 16, 0, 0);
}

// ---------------------------------------------------------------------------
// fp32 -> bf16 elementwise convert (n multiple of 2048)
// ---------------------------------------------------------------------------
__global__ __launch_bounds__(256) void cvt_bf16(
    const float* __restrict__ in, unsigned short* __restrict__ out, int n)
{
    int i = (blockIdx.x * 256 + threadIdx.x) * 8;
    if (i >= n) return;
    float4 a = *(const float4*)(in + i);
    float4 b = *(const float4*)(in + i + 4);
    uint4 o;
    o.x = pk_bf16(a.x, a.y); o.y = pk_bf16(a.z, a.w);
    o.z = pk_bf16(b.x, b.y); o.w = pk_bf16(b.z, b.w);
    *(uint4*)(out + i) = o;
}

// ---------------------------------------------------------------------------
// W [K][N] fp32 -> Wt [N][K] bf16  (64x64 LDS tiles)
// ---------------------------------------------------------------------------
__global__ __launch_bounds__(256) void wt_cvt(
    const float* __restrict__ W, unsigned short* __restrict__ Wt, int K, int N)
{
    __shared__ float T[64 * 65];
    const int tid = threadIdx.x;
    const int n0 = blockIdx.x << 6, k0 = blockIdx.y << 6;
    #pragma unroll
    for (int i = 0; i < 4; ++i) {
        int idx = tid + (i << 8);
        int row = idx >> 4, c4 = idx & 15;   // row = k
        float4 v = *(const float4*)(W + (size_t)(k0 + row) * N + n0 + (c4 << 2));
        float* tp = &T[row * 65 + (c4 << 2)];
        tp[0] = v.x; tp[1] = v.y; tp[2] = v.z; tp[3] = v.w;
    }
    __syncthreads();
    #pragma unroll
    for (int i = 0; i < 4; ++i) {
        int idx = tid + (i << 8);
        int n = idx >> 4, c4 = idx & 15;     // c4 indexes k-quad
        float x = T[(c4 * 4 + 0) * 65 + n];
        float y = T[(c4 * 4 + 1) * 65 + n];
        float z = T[(c4 * 4 + 2) * 65 + n];
        float w = T[(c4 * 4 + 3) * 65 + n];
        uint2 o = make_uint2(pk_bf16(x, y), pk_bf16(z, w));
        *(uint2*)(Wt + (size_t)(n0 + n) * K + k0 + (c4 << 2)) = o;
    }
}

// ---------------------------------------------------------------------------
// bf16 MFMA GEMM (m97 structure): C = A @ Wt^T + bias
// A [M][K] bf16 row-major, Wt [N][K] bf16 row-major, bias [N] fp32.
// 128x128 tile, 4 waves x 64x64, BK=32, global_load_lds width-16 staging.
// OUTMODE 0: fp32 C1[m*N+n]
// OUTMODE 1: bf16 head layout C1[((b*NH+h)*SEQ+s)*HD+dd]
// OUTMODE 2: split KV bf16: n<FDIM -> C1 (K), else C2 (V), head layout
// ---------------------------------------------------------------------------
template <int OUTMODE>
__global__ __launch_bounds__(256) void gemm_mfma(
    const unsigned short* __restrict__ A, const unsigned short* __restrict__ Wt,
    const float* __restrict__ bias, void* __restrict__ C1, void* __restrict__ C2,
    int M, int N, int K)
{
    __shared__ unsigned short Al[128 * 32];   // [m][k] 8 KB, NO pad (global_load_lds)
    __shared__ unsigned short Bl[128 * 32];   // [n][k] 8 KB

    const int tid  = threadIdx.x;
    const int w    = tid >> 6;
    const int lane = tid & 63;
    const int q    = lane >> 4, l = lane & 15;
    const int m0 = blockIdx.y * 128, n0 = blockIdx.x * 128;
    const int wm = (w >> 1) * 64, wn = (w & 1) * 64;

    floatx4 acc[4][4];
    #pragma unroll
    for (int i = 0; i < 4; ++i)
        #pragma unroll
        for (int j = 0; j < 4; ++j)
            acc[i][j] = (floatx4){0.f, 0.f, 0.f, 0.f};

    for (int k0 = 0; k0 < K; k0 += 32) {
        __syncthreads();   // prior-iter LDS reads complete
        #pragma unroll
        for (int it = 0; it < 2; ++it) {
            int c = (w * 2 + it) * 64 + lane;          // 0..511 chunk id
            int row = c >> 2, o = (c & 3) * 8;
            load16_lds(A  + (size_t)(m0 + row) * K + k0 + o, Al + c * 8);
            load16_lds(Wt + (size_t)(n0 + row) * K + k0 + o, Bl + c * 8);
        }
        __syncthreads();   // drains vmcnt (global_load_lds) too

        short8 aF[4], bF[4];
        #pragma unroll
        for (int i = 0; i < 4; ++i)
            aF[i] = *(const short8*)(Al + (wm + 16 * i + l) * 32 + 8 * q);
        #pragma unroll
        for (int j = 0; j < 4; ++j)
            bF[j] = *(const short8*)(Bl + (wn + 16 * j + l) * 32 + 8 * q);
        #pragma unroll
        for (int i = 0; i < 4; ++i)
            #pragma unroll
            for (int j = 0; j < 4; ++j)
                acc[i][j] = __builtin_amdgcn_mfma_f32_16x16x32_bf16(
                    aF[i], bF[j], acc[i][j], 0, 0, 0);
    }

    float bj[4];
    #pragma unroll
    for (int j = 0; j < 4; ++j) bj[j] = bias[n0 + wn + 16 * j + l];

    #pragma unroll
    for (int i = 0; i < 4; ++i) {
        #pragma unroll
        for (int j = 0; j < 4; ++j) {
            int n = n0 + wn + 16 * j + l;
            #pragma unroll
            for (int r = 0; r < 4; ++r) {
                int m = m0 + wm + 16 * i + 4 * q + r;
                float v = acc[i][j][r] + bj[j];
                if (OUTMODE == 0) {
                    ((float*)C1)[(size_t)m * N + n] = v;
                } else if (OUTMODE == 1) {
                    int b = m >> 11, s = m & (SEQ - 1);
                    int h = n >> 6, dd = n & 63;
                    ((unsigned short*)C1)[((size_t)(b * NH + h) * SEQ + s) * HD + dd] = bf16_1(v);
                } else {
                    int b = m >> 11, z = m & (SEQ - 1);
                    int np = (n < FDIM) ? n : (n - FDIM);
                    unsigned short* Cd = (n < FDIM) ? (unsigned short*)C1 : (unsigned short*)C2;
                    int h = np >> 6, dd = np & 63;
                    Cd[((size_t)(b * NH + h) * SEQ + z) * HD + dd] = bf16_1(v);
                }
            }
        }
    }
}

// ---------------------------------------------------------------------------
// V [bh][z][d] bf16 -> Vt [bh][d][z] bf16
// ---------------------------------------------------------------------------
__global__ __launch_bounds__(256) void transpose_v(
    const unsigned short* __restrict__ V, unsigned short* __restrict__ Vt)
{
    __shared__ unsigned short T[64 * 72];
    const int tid = threadIdx.x;
    const int zt = blockIdx.x & 31, bh = blockIdx.x >> 5;
    const int z0 = zt << 6;
    #pragma unroll
    for (int it = 0; it < 2; ++it) {
        int idx = tid + (it << 8);
        int row = idx >> 3, c8 = idx & 7;
        *(short8*)(&T[row * 72 + c8 * 8]) =
            *(const short8*)(V + ((size_t)bh * SEQ + z0 + row) * HD + c8 * 8);
    }
    __syncthreads();
    #pragma unroll
    for (int it = 0; it < 4; ++it) {
        int idx = tid + (it << 8);
        int d = idx >> 4, c4 = idx & 15;
        unsigned short a = T[(c4 * 4 + 0) * 72 + d];
        unsigned short b = T[(c4 * 4 + 1) * 72 + d];
        unsigned short c = T[(c4 * 4 + 2) * 72 + d];
        unsigned short e = T[(c4 * 4 + 3) * 72 + d];
        uint2 o = make_uint2((unsigned)a | ((unsigned)b << 16),
                             (unsigned)c | ((unsigned)e << 16));
        *(uint2*)(Vt + ((size_t)bh * HD + d) * SEQ + z0 + (c4 << 2)) = o;
    }
}

// ---------------------------------------------------------------------------
// Flash attention, bf16 MFMA 16x16x32, fp32 softmax. All operands bf16.
// Masked logits = exactly -1e12f (row 0 fully masked -> uniform softmax).
// ---------------------------------------------------------------------------
__global__ __launch_bounds__(256) void attn_kernel(
    const unsigned short* __restrict__ Qg, const unsigned short* __restrict__ Kg,
    const unsigned short* __restrict__ Vtg, unsigned short* __restrict__ Og)
{
    __shared__ unsigned short Kl[64 * LK];
    __shared__ unsigned short Vl[64 * LK];
    __shared__ unsigned short Pl[4 * 16 * LK];

    const int tid  = threadIdx.x;
    const int w    = tid >> 6;
    const int lane = tid & 63;
    const int q    = lane >> 4;
    const int l    = lane & 15;

    const int bid = blockIdx.x;
    const int bh  = bid & (BH - 1);
    const int t_o = bid >> 5;                      // heavy tiles first
    const int st  = (t_o == 0) ? 0 : (32 - t_o);
    const int s0  = st << 6;

    const unsigned short* Qb  = Qg  + (size_t)bh * SEQ * HD;
    const unsigned short* Kb  = Kg  + (size_t)bh * SEQ * HD;
    const unsigned short* Vtb = Vtg + (size_t)bh * HD * SEQ;

    short8 aQ[2];
    {
        const unsigned short* qp = Qb + (size_t)(s0 + 16 * w + l) * HD + 8 * q;
        aQ[0] = *(const short8*)(qp);
        aQ[1] = *(const short8*)(qp + 32);
    }

    float m_run[4], l_run[4];
    floatx4 oacc[4];
    #pragma unroll
    for (int r = 0; r < 4; ++r) { m_run[r] = -INFINITY; l_run[r] = 0.f; }
    #pragma unroll
    for (int nd = 0; nd < 4; ++nd) oacc[nd] = (floatx4){0.f, 0.f, 0.f, 0.f};

    const int ntiles = (st == 0) ? (SEQ >> 6) : (st + 1);

    for (int zt = 0; zt < ntiles; ++zt) {
        const int z0 = zt << 6;
        __syncthreads();
        #pragma unroll
        for (int it = 0; it < 2; ++it) {
            int idx = tid + (it << 8);
            int row = idx >> 3, c8 = idx & 7;
            *(short8*)(&Kl[row * LK + c8 * 8]) =
                *(const short8*)(Kb + (size_t)(z0 + row) * HD + c8 * 8);
            *(short8*)(&Vl[row * LK + c8 * 8]) =
                *(const short8*)(Vtb + (size_t)row * SEQ + z0 + c8 * 8);
        }
        __syncthreads();

        floatx4 sacc[4];
        #pragma unroll
        for (int t = 0; t < 4; ++t) {
            sacc[t] = (floatx4){0.f, 0.f, 0.f, 0.f};
            short8 b0 = *(const short8*)(&Kl[(16 * t + l) * LK + 8 * q]);
            short8 b1 = *(const short8*)(&Kl[(16 * t + l) * LK + 8 * q + 32]);
            sacc[t] = __builtin_amdgcn_mfma_f32_16x16x32_bf16(aQ[0], b0, sacc[t], 0, 0, 0);
            sacc[t] = __builtin_amdgcn_mfma_f32_16x16x32_bf16(aQ[1], b1, sacc[t], 0, 0, 0);
        }

        #pragma unroll
        for (int t = 0; t < 4; ++t) {
            int z = z0 + 16 * t + l;
            #pragma unroll
            for (int r = 0; r < 4; ++r) {
                int s = s0 + 16 * w + 4 * q + r;
                if (z >= s) sacc[t][r] = -1e12f;
            }
        }

        #pragma unroll
        for (int r = 0; r < 4; ++r) {
            float rm = fmaxf(fmaxf(sacc[0][r], sacc[1][r]),
                             fmaxf(sacc[2][r], sacc[3][r]));
            rm = fmaxf(rm, __shfl_xor(rm, 1, 64));
            rm = fmaxf(rm, __shfl_xor(rm, 2, 64));
            rm = fmaxf(rm, __shfl_xor(rm, 4, 64));
            rm = fmaxf(rm, __shfl_xor(rm, 8, 64));
            float mn = fmaxf(m_run[r], rm);
            float rs = 0.f;
            #pragma unroll
            for (int t = 0; t < 4; ++t) {
                float pe = __expf(sacc[t][r] - mn);
                sacc[t][r] = pe;
                rs += pe;
            }
            rs += __shfl_xor(rs, 1, 64);
            rs += __shfl_xor(rs, 2, 64);
            rs += __shfl_xor(rs, 4, 64);
            rs += __shfl_xor(rs, 8, 64);
            float alpha = __expf(m_run[r] - mn);
            l_run[r] = alpha * l_run[r] + rs;
            m_run[r] = mn;
            #pragma unroll
            for (int nd = 0; nd < 4; ++nd) oacc[nd][r] *= alpha;
        }

        unsigned short* Pw = &Pl[w * 16 * LK];
        #pragma unroll
        for (int t = 0; t < 4; ++t)
            #pragma unroll
            for (int r = 0; r < 4; ++r)
                Pw[(4 * q + r) * LK + 16 * t + l] = bf16_1(sacc[t][r]);

        short8 aP0 = *(const short8*)(&Pw[l * LK + 8 * q]);
        short8 aP1 = *(const short8*)(&Pw[l * LK + 8 * q + 32]);
        #pragma unroll
        for (int nd = 0; nd < 4; ++nd) {
            short8 b0 = *(const short8*)(&Vl[(16 * nd + l) * LK + 8 * q]);
            short8 b1 = *(const short8*)(&Vl[(16 * nd + l) * LK + 8 * q + 32]);
            oacc[nd] = __builtin_amdgcn_mfma_f32_16x16x32_bf16(aP0, b0, oacc[nd], 0, 0, 0);
            oacc[nd] = __builtin_amdgcn_mfma_f32_16x16x32_bf16(aP1, b1, oacc[nd], 0, 0, 0);
        }
    }

    // epilogue: O/l -> bf16 [B*S][F] row-major (A operand of out-GEMM)
    const int b = bh >> 4, h = bh & 15;
    #pragma unroll
    for (int r = 0; r < 4; ++r) {
        float inv = 1.0f / l_run[r];
        int s = s0 + 16 * w + 4 * q + r;
        unsigned short* op = Og + ((size_t)b * SEQ + s) * FDIM + h * HD;
        #pragma unroll
        for (int nd = 0; nd < 4; ++nd)
            op[16 * nd + l] = bf16_1(oacc[nd][r] * inv);
    }
}

// ---------------------------------------------------------------------------
extern "C" void kernel_launch(void* const* d_in, const int* in_sizes, int n_in,
                              void* d_out, int out_size, void* d_ws, size_t ws_size,
                              hipStream_t stream) {
    const float* attend_from = (const float*)d_in[0];
    const float* attend_to   = (const float*)d_in[1];
    const float* w_q   = (const float*)d_in[2];
    const float* b_q   = (const float*)d_in[3];
    const float* w_kv  = (const float*)d_in[4];
    const float* b_kv  = (const float*)d_in[5];
    const float* w_out = (const float*)d_in[6];
    const float* b_out = (const float*)d_in[7];
    float* out = (float*)d_out;

    unsigned short* ws = (unsigned short*)d_ws;
    const size_t E = (size_t)(SB * SEQ) * FDIM;   // 4M elems
    unsigned short* Af   = ws;
    unsigned short* At   = ws + E;
    unsigned short* Qb   = ws + 2 * E;
    unsigned short* Kb   = ws + 3 * E;
    unsigned short* Vb   = ws + 4 * E;
    unsigned short* Vt   = ws + 5 * E;
    unsigned short* Ob   = Vb;                    // reuse V after transpose
    unsigned short* Wqt  = ws + 6 * E;
    unsigned short* Wkvt = ws + 6 * E + E / 4;
    unsigned short* Wot  = ws + 6 * E + E / 4 + E / 2;

    dim3 blk(256);
    const int M = SB * SEQ;   // 4096
    const int n_cvt = (int)E;

    cvt_bf16<<<dim3(n_cvt / 2048), blk, 0, stream>>>(attend_from, Af, n_cvt);
    cvt_bf16<<<dim3(n_cvt / 2048), blk, 0, stream>>>(attend_to,   At, n_cvt);
    wt_cvt<<<dim3(FDIM / 64, FDIM / 64), blk, 0, stream>>>(w_q,   Wqt,  FDIM, FDIM);
    wt_cvt<<<dim3(2 * FDIM / 64, FDIM / 64), blk, 0, stream>>>(w_kv, Wkvt, FDIM, 2 * FDIM);
    wt_cvt<<<dim3(FDIM / 64, FDIM / 64), blk, 0, stream>>>(w_out, Wot,  FDIM, FDIM);

    gemm_mfma<1><<<dim3(FDIM / 128, M / 128), blk, 0, stream>>>(
        Af, Wqt, b_q, Qb, nullptr, M, FDIM, FDIM);
    gemm_mfma<2><<<dim3(2 * FDIM / 128, M / 128), blk, 0, stream>>>(
        At, Wkvt, b_kv, Kb, Vb, M, 2 * FDIM, FDIM);
    transpose_v<<<dim3(BH * (SEQ / 64)), blk, 0, stream>>>(Vb, Vt);
    attn_kernel<<<dim3(BH * (SEQ / 64)), blk, 0, stream>>>(Qb, Kb, Vt, Ob);
    gemm_mfma<0><<<dim3(FDIM / 128, M / 128), blk, 0, stream>>>(
        Ob, Wot, b_out, out, nullptr, M, FDIM, FDIM);
}

// Round 5
// 225.968 us; speedup vs baseline: 5.7001x; 1.1701x over previous
//
#include <hip/hip_runtime.h>
#include <math.h>

#define SB   2
#define SEQ  2048
#define FDIM 1024
#define NH   16
#define HD   64
#define BH   (SB * NH)   // 32
#define LK   72          // attention LDS row stride in f16 elems (64 + 8 pad)

typedef _Float16 half8 __attribute__((ext_vector_type(8)));
typedef __attribute__((ext_vector_type(4))) float floatx4;

__device__ __forceinline__ unsigned pk_f16(float a, float b) {
    unsigned short ha = __builtin_bit_cast(unsigned short, (_Float16)a);
    unsigned short hb = __builtin_bit_cast(unsigned short, (_Float16)b);
    return (unsigned)ha | ((unsigned)hb << 16);
}
__device__ __forceinline__ unsigned short f16_1(float a) {
    _Float16 h = (_Float16)a;
    return __builtin_bit_cast(unsigned short, h);
}
__device__ __forceinline__ void load16_lds(const unsigned short* g, unsigned short* l) {
    __builtin_amdgcn_global_load_lds(
        (const __attribute__((address_space(1))) unsigned int*)g,
        (__attribute__((address_space(3))) unsigned int*)l, 16, 0, 0);
}

// ---------------------------------------------------------------------------
// fp32 -> f16: both activations in one launch. blockIdx.x < 2048 -> from.
// ---------------------------------------------------------------------------
__global__ __launch_bounds__(256) void cvt_act(
    const float* __restrict__ in0, const float* __restrict__ in1,
    unsigned short* __restrict__ out0, unsigned short* __restrict__ out1)
{
    int bx = blockIdx.x;
    const float* in = (bx < 2048) ? in0 : in1;
    unsigned short* out = (bx < 2048) ? out0 : out1;
    int i = ((bx & 2047) * 256 + threadIdx.x) * 8;
    float4 a = *(const float4*)(in + i);
    float4 b = *(const float4*)(in + i + 4);
    uint4 o;
    o.x = pk_f16(a.x, a.y); o.y = pk_f16(a.z, a.w);
    o.z = pk_f16(b.x, b.y); o.w = pk_f16(b.z, b.w);
    *(uint4*)(out + i) = o;
}

// ---------------------------------------------------------------------------
// All three W [K][N] fp32 -> Wt [N][K] f16 in one launch (64x64 LDS tiles).
// blocks: [0,256) w_q (N=1024), [256,768) w_kv (N=2048), [768,1024) w_out.
// ---------------------------------------------------------------------------
__global__ __launch_bounds__(256) void cvt_w(
    const float* __restrict__ Wq, const float* __restrict__ Wkv,
    const float* __restrict__ Wo, unsigned short* __restrict__ Wqt,
    unsigned short* __restrict__ Wkvt, unsigned short* __restrict__ Wot)
{
    __shared__ float T[64 * 65];
    const int tid = threadIdx.x;
    int id = blockIdx.x;
    const float* W; unsigned short* Wt; int N, n0, k0;
    if (id < 256)      { W = Wq;  Wt = Wqt;  N = 1024; n0 = (id & 15) << 6; k0 = (id >> 4) << 6; }
    else if (id < 768) { id -= 256; W = Wkv; Wt = Wkvt; N = 2048; n0 = (id & 31) << 6; k0 = (id >> 5) << 6; }
    else               { id -= 768; W = Wo;  Wt = Wot;  N = 1024; n0 = (id & 15) << 6; k0 = (id >> 4) << 6; }

    #pragma unroll
    for (int i = 0; i < 4; ++i) {
        int idx = tid + (i << 8);
        int row = idx >> 4, c4 = idx & 15;
        float4 v = *(const float4*)(W + (size_t)(k0 + row) * N + n0 + (c4 << 2));
        float* tp = &T[row * 65 + (c4 << 2)];
        tp[0] = v.x; tp[1] = v.y; tp[2] = v.z; tp[3] = v.w;
    }
    __syncthreads();
    #pragma unroll
    for (int i = 0; i < 4; ++i) {
        int idx = tid + (i << 8);
        int n = idx >> 4, c4 = idx & 15;
        float x = T[(c4 * 4 + 0) * 65 + n];
        float y = T[(c4 * 4 + 1) * 65 + n];
        float z = T[(c4 * 4 + 2) * 65 + n];
        float w = T[(c4 * 4 + 3) * 65 + n];
        uint2 o = make_uint2(pk_f16(x, y), pk_f16(z, w));
        *(uint2*)(Wt + (size_t)(n0 + n) * FDIM + k0 + (c4 << 2)) = o;
    }
}

// ---------------------------------------------------------------------------
// f16 MFMA GEMM core (m97 structure): acc = A @ Wt^T, 128x128 tile, BK=32.
// ---------------------------------------------------------------------------
__device__ __forceinline__ void gemm_core(
    const unsigned short* __restrict__ A, const unsigned short* __restrict__ Wt,
    int m0, int n0, int K, floatx4 (&acc)[4][4],
    unsigned short* Al, unsigned short* Bl)
{
    const int tid  = threadIdx.x;
    const int w    = tid >> 6;
    const int lane = tid & 63;
    const int q    = lane >> 4, l = lane & 15;
    const int wm = (w >> 1) * 64, wn = (w & 1) * 64;

    for (int k0 = 0; k0 < K; k0 += 32) {
        __syncthreads();
        #pragma unroll
        for (int it = 0; it < 2; ++it) {
            int c = (w * 2 + it) * 64 + lane;
            int row = c >> 2, o = (c & 3) * 8;
            load16_lds(A  + (size_t)(m0 + row) * K + k0 + o, Al + c * 8);
            load16_lds(Wt + (size_t)(n0 + row) * K + k0 + o, Bl + c * 8);
        }
        __syncthreads();

        half8 aF[4], bF[4];
        #pragma unroll
        for (int i = 0; i < 4; ++i)
            aF[i] = *(const half8*)(Al + (wm + 16 * i + l) * 32 + 8 * q);
        #pragma unroll
        for (int j = 0; j < 4; ++j)
            bF[j] = *(const half8*)(Bl + (wn + 16 * j + l) * 32 + 8 * q);
        #pragma unroll
        for (int i = 0; i < 4; ++i)
            #pragma unroll
            for (int j = 0; j < 4; ++j)
                acc[i][j] = __builtin_amdgcn_mfma_f32_16x16x32_f16(
                    aF[i], bF[j], acc[i][j], 0, 0, 0);
    }
}

// ---------------------------------------------------------------------------
// Merged Q + KV projection GEMM. grid (24, 32): bx<8 -> Q, else KV.
// Outputs f16 head layout [(b*NH+h)*SEQ + s]*HD + dd.
// ---------------------------------------------------------------------------
__global__ __launch_bounds__(256) void gemm_qkv(
    const unsigned short* __restrict__ Af, const unsigned short* __restrict__ At,
    const unsigned short* __restrict__ Wqt, const unsigned short* __restrict__ Wkvt,
    const float* __restrict__ bq, const float* __restrict__ bkv,
    unsigned short* __restrict__ Qo, unsigned short* __restrict__ Ko,
    unsigned short* __restrict__ Vo)
{
    __shared__ unsigned short Al[128 * 32];
    __shared__ unsigned short Bl[128 * 32];

    const int tid  = threadIdx.x;
    const int w    = tid >> 6;
    const int lane = tid & 63;
    const int q    = lane >> 4, l = lane & 15;
    const int wm = (w >> 1) * 64, wn = (w & 1) * 64;
    const int m0 = blockIdx.y * 128;

    bool isQ = blockIdx.x < 8;
    const unsigned short* A  = isQ ? Af : At;
    const unsigned short* Wt = isQ ? Wqt : Wkvt;
    const float* bias        = isQ ? bq : bkv;
    const int n0 = (isQ ? blockIdx.x : (blockIdx.x - 8)) * 128;

    floatx4 acc[4][4];
    #pragma unroll
    for (int i = 0; i < 4; ++i)
        #pragma unroll
        for (int j = 0; j < 4; ++j)
            acc[i][j] = (floatx4){0.f, 0.f, 0.f, 0.f};

    gemm_core(A, Wt, m0, n0, FDIM, acc, Al, Bl);

    float bj[4];
    #pragma unroll
    for (int j = 0; j < 4; ++j) bj[j] = bias[n0 + wn + 16 * j + l];

    #pragma unroll
    for (int i = 0; i < 4; ++i)
        #pragma unroll
        for (int j = 0; j < 4; ++j) {
            int n = n0 + wn + 16 * j + l;
            #pragma unroll
            for (int r = 0; r < 4; ++r) {
                int m = m0 + wm + 16 * i + 4 * q + r;
                float v = acc[i][j][r] + bj[j];
                int b = m >> 11, s = m & (SEQ - 1);
                if (isQ) {
                    int h = n >> 6, dd = n & 63;
                    Qo[((size_t)(b * NH + h) * SEQ + s) * HD + dd] = f16_1(v);
                } else {
                    int np = (n < FDIM) ? n : (n - FDIM);
                    unsigned short* Cd = (n < FDIM) ? Ko : Vo;
                    int h = np >> 6, dd = np & 63;
                    Cd[((size_t)(b * NH + h) * SEQ + s) * HD + dd] = f16_1(v);
                }
            }
        }
}

// ---------------------------------------------------------------------------
// Out-projection GEMM: fp32 output [M][N].
// ---------------------------------------------------------------------------
__global__ __launch_bounds__(256) void gemm_out(
    const unsigned short* __restrict__ A, const unsigned short* __restrict__ Wt,
    const float* __restrict__ bias, float* __restrict__ C)
{
    __shared__ unsigned short Al[128 * 32];
    __shared__ unsigned short Bl[128 * 32];

    const int tid  = threadIdx.x;
    const int w    = tid >> 6;
    const int lane = tid & 63;
    const int q    = lane >> 4, l = lane & 15;
    const int wm = (w >> 1) * 64, wn = (w & 1) * 64;
    const int m0 = blockIdx.y * 128, n0 = blockIdx.x * 128;

    floatx4 acc[4][4];
    #pragma unroll
    for (int i = 0; i < 4; ++i)
        #pragma unroll
        for (int j = 0; j < 4; ++j)
            acc[i][j] = (floatx4){0.f, 0.f, 0.f, 0.f};

    gemm_core(A, Wt, m0, n0, FDIM, acc, Al, Bl);

    float bj[4];
    #pragma unroll
    for (int j = 0; j < 4; ++j) bj[j] = bias[n0 + wn + 16 * j + l];

    #pragma unroll
    for (int i = 0; i < 4; ++i)
        #pragma unroll
        for (int j = 0; j < 4; ++j) {
            int n = n0 + wn + 16 * j + l;
            #pragma unroll
            for (int r = 0; r < 4; ++r) {
                int m = m0 + wm + 16 * i + 4 * q + r;
                C[(size_t)m * FDIM + n] = acc[i][j][r] + bj[j];
            }
        }
}

// ---------------------------------------------------------------------------
// V [bh][z][d] f16 -> Vt [bh][d][z] f16
// ---------------------------------------------------------------------------
__global__ __launch_bounds__(256) void transpose_v(
    const unsigned short* __restrict__ V, unsigned short* __restrict__ Vt)
{
    __shared__ unsigned short T[64 * 72];
    const int tid = threadIdx.x;
    const int zt = blockIdx.x & 31, bh = blockIdx.x >> 5;
    const int z0 = zt << 6;
    #pragma unroll
    for (int it = 0; it < 2; ++it) {
        int idx = tid + (it << 8);
        int row = idx >> 3, c8 = idx & 7;
        *(half8*)(&T[row * 72 + c8 * 8]) =
            *(const half8*)(V + ((size_t)bh * SEQ + z0 + row) * HD + c8 * 8);
    }
    __syncthreads();
    #pragma unroll
    for (int it = 0; it < 4; ++it) {
        int idx = tid + (it << 8);
        int d = idx >> 4, c4 = idx & 15;
        unsigned short a = T[(c4 * 4 + 0) * 72 + d];
        unsigned short b = T[(c4 * 4 + 1) * 72 + d];
        unsigned short c = T[(c4 * 4 + 2) * 72 + d];
        unsigned short e = T[(c4 * 4 + 3) * 72 + d];
        uint2 o = make_uint2((unsigned)a | ((unsigned)b << 16),
                             (unsigned)c | ((unsigned)e << 16));
        *(uint2*)(Vt + ((size_t)bh * HD + d) * SEQ + z0 + (c4 << 2)) = o;
    }
}

// ---------------------------------------------------------------------------
// Flash attention, f16 MFMA 16x16x32, fp32 softmax.
// Row sums via ones-MFMA (no sum shuffles). Row 0 masked with 0.0f (all-masked
// row -> p=1 uniform, matching ref); other masked logits = exactly -1e12f.
// ---------------------------------------------------------------------------
__global__ __launch_bounds__(256) void attn_kernel(
    const unsigned short* __restrict__ Qg, const unsigned short* __restrict__ Kg,
    const unsigned short* __restrict__ Vtg, unsigned short* __restrict__ Og)
{
    __shared__ unsigned short Kl[64 * LK];
    __shared__ unsigned short Vl[64 * LK];
    __shared__ unsigned short Pl[4 * 16 * LK];

    const int tid  = threadIdx.x;
    const int w    = tid >> 6;
    const int lane = tid & 63;
    const int q    = lane >> 4;
    const int l    = lane & 15;

    const int bid = blockIdx.x;
    const int bh  = bid & (BH - 1);
    const int t_o = bid >> 5;                      // heavy tiles first
    const int st  = (t_o == 0) ? 0 : (32 - t_o);
    const int s0  = st << 6;

    const unsigned short* Qb  = Qg  + (size_t)bh * SEQ * HD;
    const unsigned short* Kb  = Kg  + (size_t)bh * SEQ * HD;
    const unsigned short* Vtb = Vtg + (size_t)bh * HD * SEQ;

    half8 aQ[2];
    {
        const unsigned short* qp = Qb + (size_t)(s0 + 16 * w + l) * HD + 8 * q;
        aQ[0] = *(const half8*)(qp);
        aQ[1] = *(const half8*)(qp + 32);
    }

    half8 ones;
    #pragma unroll
    for (int j = 0; j < 8; ++j) ones[j] = (_Float16)1.0f;

    float m_run[4], l_run[4];
    floatx4 oacc[4];
    #pragma unroll
    for (int r = 0; r < 4; ++r) { m_run[r] = -INFINITY; l_run[r] = 0.f; }
    #pragma unroll
    for (int nd = 0; nd < 4; ++nd) oacc[nd] = (floatx4){0.f, 0.f, 0.f, 0.f};

    const int ntiles = (st == 0) ? (SEQ >> 6) : (st + 1);

    for (int zt = 0; zt < ntiles; ++zt) {
        const int z0 = zt << 6;
        __syncthreads();
        #pragma unroll
        for (int it = 0; it < 2; ++it) {
            int idx = tid + (it << 8);
            int row = idx >> 3, c8 = idx & 7;
            *(half8*)(&Kl[row * LK + c8 * 8]) =
                *(const half8*)(Kb + (size_t)(z0 + row) * HD + c8 * 8);
            *(half8*)(&Vl[row * LK + c8 * 8]) =
                *(const half8*)(Vtb + (size_t)row * SEQ + z0 + c8 * 8);
        }
        __syncthreads();

        floatx4 sacc[4];
        #pragma unroll
        for (int t = 0; t < 4; ++t) {
            sacc[t] = (floatx4){0.f, 0.f, 0.f, 0.f};
            half8 b0 = *(const half8*)(&Kl[(16 * t + l) * LK + 8 * q]);
            half8 b1 = *(const half8*)(&Kl[(16 * t + l) * LK + 8 * q + 32]);
            sacc[t] = __builtin_amdgcn_mfma_f32_16x16x32_f16(aQ[0], b0, sacc[t], 0, 0, 0);
            sacc[t] = __builtin_amdgcn_mfma_f32_16x16x32_f16(aQ[1], b1, sacc[t], 0, 0, 0);
        }

        // mask: z >= s. Row 0 (globally all-masked) -> 0.0f so p=1 uniform.
        #pragma unroll
        for (int t = 0; t < 4; ++t) {
            int z = z0 + 16 * t + l;
            #pragma unroll
            for (int r = 0; r < 4; ++r) {
                int s = s0 + 16 * w + 4 * q + r;
                if (z >= s) sacc[t][r] = (s == 0) ? 0.0f : -1e12f;
            }
        }

        // row max (16-lane shuffle) -> mn, alpha; exp in fp32
        float alpha[4];
        #pragma unroll
        for (int r = 0; r < 4; ++r) {
            float rm = fmaxf(fmaxf(sacc[0][r], sacc[1][r]),
                             fmaxf(sacc[2][r], sacc[3][r]));
            rm = fmaxf(rm, __shfl_xor(rm, 1, 64));
            rm = fmaxf(rm, __shfl_xor(rm, 2, 64));
            rm = fmaxf(rm, __shfl_xor(rm, 4, 64));
            rm = fmaxf(rm, __shfl_xor(rm, 8, 64));
            float mn = fmaxf(m_run[r], rm);
            #pragma unroll
            for (int t = 0; t < 4; ++t)
                sacc[t][r] = __expf(sacc[t][r] - mn);
            alpha[r] = __expf(m_run[r] - mn);
            m_run[r] = mn;
            #pragma unroll
            for (int nd = 0; nd < 4; ++nd) oacc[nd][r] *= alpha[r];
        }

        // P -> per-wave LDS strip as f16 (same-wave write->read, no barrier)
        unsigned short* Pw = &Pl[w * 16 * LK];
        #pragma unroll
        for (int t = 0; t < 4; ++t)
            #pragma unroll
            for (int r = 0; r < 4; ++r)
                Pw[(4 * q + r) * LK + 16 * t + l] = f16_1(sacc[t][r]);

        half8 aP0 = *(const half8*)(&Pw[l * LK + 8 * q]);
        half8 aP1 = *(const half8*)(&Pw[l * LK + 8 * q + 32]);

        // row sums via ones-MFMA (replaces 16 shuffle ops)
        floatx4 ls = (floatx4){0.f, 0.f, 0.f, 0.f};
        ls = __builtin_amdgcn_mfma_f32_16x16x32_f16(aP0, ones, ls, 0, 0, 0);
        ls = __builtin_amdgcn_mfma_f32_16x16x32_f16(aP1, ones, ls, 0, 0, 0);
        #pragma unroll
        for (int r = 0; r < 4; ++r)
            l_run[r] = alpha[r] * l_run[r] + ls[r];

        // O += P @ V
        #pragma unroll
        for (int nd = 0; nd < 4; ++nd) {
            half8 b0 = *(const half8*)(&Vl[(16 * nd + l) * LK + 8 * q]);
            half8 b1 = *(const half8*)(&Vl[(16 * nd + l) * LK + 8 * q + 32]);
            oacc[nd] = __builtin_amdgcn_mfma_f32_16x16x32_f16(aP0, b0, oacc[nd], 0, 0, 0);
            oacc[nd] = __builtin_amdgcn_mfma_f32_16x16x32_f16(aP1, b1, oacc[nd], 0, 0, 0);
        }
    }

    // epilogue: O/l -> f16 [B*S][F] row-major (A operand of out-GEMM)
    const int b = bh >> 4, h = bh & 15;
    #pragma unroll
    for (int r = 0; r < 4; ++r) {
        float inv = 1.0f / l_run[r];
        int s = s0 + 16 * w + 4 * q + r;
        unsigned short* op = Og + ((size_t)b * SEQ + s) * FDIM + h * HD;
        #pragma unroll
        for (int nd = 0; nd < 4; ++nd)
            op[16 * nd + l] = f16_1(oacc[nd][r] * inv);
    }
}

// ---------------------------------------------------------------------------
extern "C" void kernel_launch(void* const* d_in, const int* in_sizes, int n_in,
                              void* d_out, int out_size, void* d_ws, size_t ws_size,
                              hipStream_t stream) {
    const float* attend_from = (const float*)d_in[0];
    const float* attend_to   = (const float*)d_in[1];
    const float* w_q   = (const float*)d_in[2];
    const float* b_q   = (const float*)d_in[3];
    const float* w_kv  = (const float*)d_in[4];
    const float* b_kv  = (const float*)d_in[5];
    const float* w_out = (const float*)d_in[6];
    const float* b_out = (const float*)d_in[7];
    float* out = (float*)d_out;

    unsigned short* ws = (unsigned short*)d_ws;
    const size_t E = (size_t)(SB * SEQ) * FDIM;   // 4M elems
    unsigned short* Af   = ws;
    unsigned short* At   = ws + E;
    unsigned short* Qb   = ws + 2 * E;
    unsigned short* Kb   = ws + 3 * E;
    unsigned short* Vb   = ws + 4 * E;
    unsigned short* Vt   = ws + 5 * E;
    unsigned short* Ob   = Vb;                    // reuse V after transpose
    unsigned short* Wqt  = ws + 6 * E;
    unsigned short* Wkvt = ws + 6 * E + E / 4;
    unsigned short* Wot  = ws + 6 * E + E / 4 + E / 2;

    dim3 blk(256);
    const int M = SB * SEQ;   // 4096

    cvt_act<<<dim3(4096), blk, 0, stream>>>(attend_from, attend_to, Af, At);
    cvt_w<<<dim3(1024), blk, 0, stream>>>(w_q, w_kv, w_out, Wqt, Wkvt, Wot);
    gemm_qkv<<<dim3(24, M / 128), blk, 0, stream>>>(
        Af, At, Wqt, Wkvt, b_q, b_kv, Qb, Kb, Vb);
    transpose_v<<<dim3(BH * (SEQ / 64)), blk, 0, stream>>>(Vb, Vt);
    attn_kernel<<<dim3(BH * (SEQ / 64)), blk, 0, stream>>>(Qb, Kb, Vt, Ob);
    gemm_out<<<dim3(FDIM / 128, M / 128), blk, 0, stream>>>(Ob, Wot, b_out, out);
}